// Round 3
// baseline (117.635 us; speedup 1.0000x reference)
//
#include <hip/hip_runtime.h>

// out[t, j] = W[j, x[t]] + b[j]
//   x : [16384] int32, W : [1024, 50257] f32 row-major, b : [1024] f32
//   out: [16384, 1024] f32
//
// Round 2: sorted-gather hit 104us but the gather dispatch ran at 820 GB/s
// HBM with ~1.07 GB of address-divergent L2-side traffic (16.8M scattered
// 4B loads, 64 TA transactions per wave-load, 4B used per 64B line per
// token).
//
// Round 3: invert the loop — one block per line-group bucket (v>>4).
// Stage W[:, 16g:16g+16] (64KB) into LDS with fully-coalesced float4 reads
// (each line read ONCE per bucket, fully consumed), then serve all tokens
// of the bucket from LDS with coalesced output writes. LDS slab is
// transposed [u][j] with row stride 516 (mod 32 == 4): staged writes are
// 2-way (free), token reads are contiguous ds_read_b64 (conflict-free).
// Slab processed in two 512-j halves -> 33KB LDS -> 4 blocks/CU.

#define VOCAB 50257
#define DIM   1024
#define NBUCK ((VOCAB + 15) >> 4)     // 3142 line-groups
#define SLAB_STRIDE 516               // 512 + 4 : stride%32==4, 16B-aligned rows
#define HALF  512

// ---------- sort pipeline (counting sort by v>>4) ----------

__global__ void zero_counts_kernel(int* __restrict__ counts, int n) {
    int i = blockIdx.x * blockDim.x + threadIdx.x;
    if (i < n) counts[i] = 0;
}

__global__ void hist_kernel(const int* __restrict__ x, int n, int* __restrict__ counts) {
    int i = blockIdx.x * blockDim.x + threadIdx.x;
    if (i < n) atomicAdd(&counts[x[i] >> 4], 1);
}

// single block, 256 threads: exclusive prefix sum over NBUCK counters
__global__ __launch_bounds__(256) void scan_kernel(const int* __restrict__ counts,
                                                   int* __restrict__ offs) {
    const int CHUNK = (NBUCK + 255) / 256;   // 13
    __shared__ int lds[256];
    const int tid = threadIdx.x;
    const int base = tid * CHUNK;
    int local[CHUNK];
    int s = 0;
#pragma unroll
    for (int k = 0; k < CHUNK; ++k) {
        int idx = base + k;
        int c = (idx < NBUCK) ? counts[idx] : 0;
        local[k] = s;
        s += c;
    }
    lds[tid] = s;
    __syncthreads();
    if (tid == 0) {
        int run = 0;
        for (int i = 0; i < 256; ++i) { int c = lds[i]; lds[i] = run; run += c; }
    }
    __syncthreads();
    const int boff = lds[tid];
#pragma unroll
    for (int k = 0; k < CHUNK; ++k) {
        int idx = base + k;
        if (idx < NBUCK) offs[idx] = boff + local[k];
    }
}

// offs consumed as running cursors (recomputed every call -> deterministic).
// Packs token id (low 16b) + u=v&15 (high bits) so gather needs no x[t] load.
__global__ void scatter_kernel(const int* __restrict__ x, int n,
                               int* __restrict__ offs, int* __restrict__ order) {
    int i = blockIdx.x * blockDim.x + threadIdx.x;
    if (i < n) {
        int v = x[i];
        int pos = atomicAdd(&offs[v >> 4], 1);
        order[pos] = i | ((v & 15) << 16);
    }
}

// ---------- bucket gather ----------
// grid = NBUCK blocks x 256 threads. ends[g] = end offset of bucket g
// (the post-scatter cursor array); start = ends[g-1].
__global__ __launch_bounds__(256) void bucket_gather_kernel(
    const float* __restrict__ W,
    const float* __restrict__ bias,
    const int* __restrict__ order,
    const int* __restrict__ ends,
    float* __restrict__ out)
{
    extern __shared__ float slab[];          // [16][SLAB_STRIDE] = 33024 B
    __shared__ int tile[256];

    const int g = blockIdx.x;
    const int end = ends[g];
    const int start = (g == 0) ? 0 : ends[g - 1];
    if (end - start == 0) return;

    const int vbase = g << 4;
    const bool full = (vbase + 15) < VOCAB;  // block-uniform
    const int tid = threadIdx.x;
    const int jsub = tid >> 2;               // 0..63
    const int u4   = (tid & 3) * 4;          // 0,4,8,12
    const int jl2  = tid * 2;                // local j pair 0..510

    for (int h = 0; h < 2; ++h) {
        // ---- stage half h: 512 j x 16 u, register-transposed into LDS ----
        float4 wv[8];
#pragma unroll
        for (int it = 0; it < 8; ++it) {
            const int j = h * HALF + it * 64 + jsub;
            const float* src = W + (size_t)j * VOCAB + vbase + u4;
            if (full) {
                wv[it] = *reinterpret_cast<const float4*>(src);
            } else {
                wv[it].x = (vbase + u4 + 0 < VOCAB) ? src[0] : 0.f;
                wv[it].y = (vbase + u4 + 1 < VOCAB) ? src[1] : 0.f;
                wv[it].z = (vbase + u4 + 2 < VOCAB) ? src[2] : 0.f;
                wv[it].w = (vbase + u4 + 3 < VOCAB) ? src[3] : 0.f;
            }
        }
        __syncthreads();                     // previous half's readers done
#pragma unroll
        for (int it = 0; it < 8; ++it) {
            const int jl = it * 64 + jsub;
            slab[(u4 + 0) * SLAB_STRIDE + jl] = wv[it].x;
            slab[(u4 + 1) * SLAB_STRIDE + jl] = wv[it].y;
            slab[(u4 + 2) * SLAB_STRIDE + jl] = wv[it].z;
            slab[(u4 + 3) * SLAB_STRIDE + jl] = wv[it].w;
        }
        __syncthreads();

        const float2 bb = *reinterpret_cast<const float2*>(bias + h * HALF + jl2);

        // ---- serve tokens from LDS, 256 per tile ----
        for (int tb = start; tb < end; tb += 256) {
            const int i = tb + tid;
            if (i < end) tile[tid] = order[i];
            __syncthreads();
            const int m = min(256, end - tb);
            for (int k = 0; k < m; ++k) {
                const int pk = tile[k];
                const int t = pk & 0xFFFF;
                const int u = pk >> 16;
                float2 r = *reinterpret_cast<const float2*>(&slab[u * SLAB_STRIDE + jl2]);
                r.x += bb.x; r.y += bb.y;
                *reinterpret_cast<float2*>(out + (size_t)t * DIM + h * HALF + jl2) = r;
            }
            __syncthreads();
        }
    }
}

// fallback (round-1 kernel) if workspace too small / n too large for packing
__global__ __launch_bounds__(256) void gather_direct_kernel(
    const int* __restrict__ x,
    const float* __restrict__ W,
    const float* __restrict__ bias,
    float* __restrict__ out)
{
    const int t = blockIdx.x;
    const int v = x[t];
    const int j0 = threadIdx.x * 4;
    float4 rr;
    rr.x = W[(size_t)(j0 + 0) * VOCAB + v];
    rr.y = W[(size_t)(j0 + 1) * VOCAB + v];
    rr.z = W[(size_t)(j0 + 2) * VOCAB + v];
    rr.w = W[(size_t)(j0 + 3) * VOCAB + v];
    const float4 bb = *reinterpret_cast<const float4*>(bias + j0);
    rr.x += bb.x; rr.y += bb.y; rr.z += bb.z; rr.w += bb.w;
    *reinterpret_cast<float4*>(out + (size_t)t * DIM + j0) = rr;
}

extern "C" void kernel_launch(void* const* d_in, const int* in_sizes, int n_in,
                              void* d_out, int out_size, void* d_ws, size_t ws_size,
                              hipStream_t stream) {
    const int*   x    = (const int*)d_in[0];
    const float* W    = (const float*)d_in[1];
    const float* bias = (const float*)d_in[2];
    float*       out  = (float*)d_out;

    const int n = in_sizes[0];           // 16384 tokens

    const size_t need = (size_t)(2 * NBUCK + n) * sizeof(int);
    if (ws_size < need || n > 65536) {   // packing uses 16 bits for token id
        gather_direct_kernel<<<n, 256, 0, stream>>>(x, W, bias, out);
        return;
    }

    int* counts = (int*)d_ws;            // [NBUCK]
    int* offs   = counts + NBUCK;        // [NBUCK] -> becomes per-bucket ends
    int* order  = offs + NBUCK;          // [n] packed (t | u<<16)

    const int tb = 256;
    zero_counts_kernel<<<(NBUCK + tb - 1) / tb, tb, 0, stream>>>(counts, NBUCK);
    hist_kernel<<<(n + tb - 1) / tb, tb, 0, stream>>>(x, n, counts);
    scan_kernel<<<1, tb, 0, stream>>>(counts, offs);
    scatter_kernel<<<(n + tb - 1) / tb, tb, 0, stream>>>(x, n, offs, order);

    const size_t slab_bytes = 16 * SLAB_STRIDE * sizeof(float);   // 33024
    bucket_gather_kernel<<<NBUCK, 256, slab_bytes, stream>>>(W, bias, order, offs, out);
}